// Round 2
// baseline (3235.758 us; speedup 1.0000x reference)
//
#include <hip/hip_runtime.h>
#include <cstdint>

#define TABLE_MASK 0x3FFFFFu   // 2^22 - 1
#define P2 2654435761u
#define P3 805459861u

__device__ __forceinline__ float sigmoidf_(float x) { return 1.0f / (1.0f + expf(-x)); }

__global__ __launch_bounds__(256)
void vapl_grid_kernel(const float* __restrict__ pos,
                      const float4* __restrict__ gauss,   // [T] x 16B
                      const float4* __restrict__ vmf,     // [T] x 32B (2 x float4)
                      float* __restrict__ out,            // [N*4] then [N*7], f32
                      int n)
{
    int p = blockIdx.x * blockDim.x + threadIdx.x;
    if (p >= n) return;

    float px = pos[3 * p + 0];
    float py = pos[3 * p + 1];
    float pz = pos[3 * p + 2];

    // npos = (pos - BB_MIN) / (BB_MAX - BB_MIN); x = npos * RES
    float x = ((px + 10.0f) / 20.0f) * 128.0f;
    float y = ((py + 10.0f) / 20.0f) * 128.0f;
    float z = ((pz + 10.0f) / 20.0f) * 128.0f;

    float fx = floorf(x), fy = floorf(y), fz = floorf(z);
    int ix = (int)fx, iy = (int)fy, iz = (int)fz;
    float wx = x - fx, wy = y - fy, wz = z - fz;

    // 27-stencil x trilinear collapses to 4x4x4 corners with per-axis weights [1-w, 1, 1, w]
    float ax[4] = {1.0f - wx, 1.0f, 1.0f, wx};
    float ay[4] = {1.0f - wy, 1.0f, 1.0f, wy};
    float az[4] = {1.0f - wz, 1.0f, 1.0f, wz};

    uint32_t hx[4], hy[4], hz[4];
#pragma unroll
    for (int i = 0; i < 4; ++i) {
        hx[i] = (uint32_t)(ix - 1 + i);                 // wraps like numpy astype(uint32)
        hy[i] = (uint32_t)(iy - 1 + i) * P2;
        hz[i] = (uint32_t)(iz - 1 + i) * P3;
    }

    float tg0 = 0.f, tg1 = 0.f, tg2 = 0.f, tg3 = 0.f;
    float tv0 = 0.f, tv1 = 0.f, tv2 = 0.f, tv3 = 0.f;
    float tv4 = 0.f, tv5 = 0.f, tv6 = 0.f, tv7 = 0.f;

    for (int k = 0; k < 4; ++k) {
        for (int j = 0; j < 4; ++j) {
            uint32_t hyz = hy[j] ^ hz[k];
            float wyz = ay[j] * az[k];
#pragma unroll
            for (int i = 0; i < 4; ++i) {
                uint32_t h = (hx[i] ^ hyz) & TABLE_MASK;
                float w = ax[i] * wyz;
                float4 g  = gauss[h];
                float4 v0 = vmf[(size_t)2 * h];
                float4 v1 = vmf[(size_t)2 * h + 1];
                tg0 = fmaf(w, g.x,  tg0);
                tg1 = fmaf(w, g.y,  tg1);
                tg2 = fmaf(w, g.z,  tg2);
                tg3 = fmaf(w, g.w,  tg3);
                tv0 = fmaf(w, v0.x, tv0);
                tv1 = fmaf(w, v0.y, tv1);
                tv2 = fmaf(w, v0.z, tv2);
                tv3 = fmaf(w, v0.w, tv3);
                tv4 = fmaf(w, v1.x, tv4);
                tv5 = fmaf(w, v1.y, tv5);
                tv6 = fmaf(w, v1.z, tv6);
                tv7 = fmaf(w, v1.w, tv7);
            }
        }
    }

    // encode
    float m0 = sigmoidf_(tg0) * 20.0f - 10.0f;
    float m1 = sigmoidf_(tg1) * 20.0f - 10.0f;
    float m2 = sigmoidf_(tg2) * 20.0f - 10.0f;
    // softplus, stable
    float var = fmaxf(tg3, 0.0f) + log1pf(expf(-fabsf(tg3)));

    float sharp = expf(tv0);
    float nrm = fmaxf(sqrtf(tv1 * tv1 + tv2 * tv2 + tv3 * tv3), 1e-12f);
    float a0 = tv1 / nrm, a1 = tv2 / nrm, a2 = tv3 / nrm;
    float amp0 = sigmoidf_(tv4);
    float amp1 = sigmoidf_(tv5);
    float amp2 = sigmoidf_(tv6);

    float* og = out + (size_t)p * 4;
    og[0] = m0;
    og[1] = m1;
    og[2] = m2;
    og[3] = var;

    float* ov = out + (size_t)n * 4 + (size_t)p * 7;
    ov[0] = sharp;
    ov[1] = a0;
    ov[2] = a1;
    ov[3] = a2;
    ov[4] = amp0;
    ov[5] = amp1;
    ov[6] = amp2;
}

extern "C" void kernel_launch(void* const* d_in, const int* in_sizes, int n_in,
                              void* d_out, int out_size, void* d_ws, size_t ws_size,
                              hipStream_t stream) {
    const float*  pos   = (const float*)d_in[0];
    const float4* gauss = (const float4*)d_in[1];
    const float4* vmf   = (const float4*)d_in[2];
    float* out = (float*)d_out;
    int n = in_sizes[0] / 3;   // 1048576

    dim3 block(256);
    dim3 grid((n + 255) / 256);
    hipLaunchKernelGGL(vapl_grid_kernel, grid, block, 0, stream, pos, gauss, vmf, out, n);
}

// Round 3
// 2382.140 us; speedup vs baseline: 1.3583x; 1.3583x over previous
//
#include <hip/hip_runtime.h>
#include <cstdint>

#define TABLE_SIZE (1u << 22)
#define TABLE_MASK 0x3FFFFFu   // 2^22 - 1
#define P2 2654435761u
#define P3 805459861u

__device__ __forceinline__ float sigmoidf_(float x) { return 1.0f / (1.0f + expf(-x)); }

// ---------- prepass: pack gauss(16B) + vmf(32B) into one 64B-aligned record ----------
__global__ __launch_bounds__(256)
void pack_tables_kernel(const float4* __restrict__ gauss,
                        const float4* __restrict__ vmf,
                        float4* __restrict__ packed)   // [T*4] float4, 64B stride
{
    uint32_t i = blockIdx.x * blockDim.x + threadIdx.x;
    if (i >= TABLE_SIZE) return;
    float4 g  = gauss[i];
    float4 v0 = vmf[(size_t)2 * i];
    float4 v1 = vmf[(size_t)2 * i + 1];
    size_t b = (size_t)i * 4;
    packed[b + 0] = g;
    packed[b + 1] = v0;
    packed[b + 2] = v1;
    // packed[b+3] left as pad (never read)
}

// ---------- main: 4x4x4 collapsed stencil, one 64B line per corner ----------
__global__ __launch_bounds__(256)
void vapl_grid_packed_kernel(const float* __restrict__ pos,
                             const float4* __restrict__ packed,
                             float* __restrict__ out,   // [N*4] then [N*7], f32
                             int n)
{
    int p = blockIdx.x * blockDim.x + threadIdx.x;
    if (p >= n) return;

    float px = pos[3 * p + 0];
    float py = pos[3 * p + 1];
    float pz = pos[3 * p + 2];

    float x = ((px + 10.0f) / 20.0f) * 128.0f;
    float y = ((py + 10.0f) / 20.0f) * 128.0f;
    float z = ((pz + 10.0f) / 20.0f) * 128.0f;

    float fx = floorf(x), fy = floorf(y), fz = floorf(z);
    int ix = (int)fx, iy = (int)fy, iz = (int)fz;
    float wx = x - fx, wy = y - fy, wz = z - fz;

    float ax[4] = {1.0f - wx, 1.0f, 1.0f, wx};
    float ay[4] = {1.0f - wy, 1.0f, 1.0f, wy};
    float az[4] = {1.0f - wz, 1.0f, 1.0f, wz};

    uint32_t hx[4], hy[4], hz[4];
#pragma unroll
    for (int i = 0; i < 4; ++i) {
        hx[i] = (uint32_t)(ix - 1 + i);
        hy[i] = (uint32_t)(iy - 1 + i) * P2;
        hz[i] = (uint32_t)(iz - 1 + i) * P3;
    }

    float tg0 = 0.f, tg1 = 0.f, tg2 = 0.f, tg3 = 0.f;
    float tv0 = 0.f, tv1 = 0.f, tv2 = 0.f, tv3 = 0.f;
    float tv4 = 0.f, tv5 = 0.f, tv6 = 0.f, tv7 = 0.f;

    for (int k = 0; k < 4; ++k) {
        for (int j = 0; j < 4; ++j) {
            uint32_t hyz = hy[j] ^ hz[k];
            float wyz = ay[j] * az[k];
#pragma unroll
            for (int i = 0; i < 4; ++i) {
                uint32_t h = (hx[i] ^ hyz) & TABLE_MASK;
                float w = ax[i] * wyz;
                size_t b = (size_t)h * 4;
                float4 g  = packed[b + 0];
                float4 v0 = packed[b + 1];
                float4 v1 = packed[b + 2];
                tg0 = fmaf(w, g.x,  tg0);
                tg1 = fmaf(w, g.y,  tg1);
                tg2 = fmaf(w, g.z,  tg2);
                tg3 = fmaf(w, g.w,  tg3);
                tv0 = fmaf(w, v0.x, tv0);
                tv1 = fmaf(w, v0.y, tv1);
                tv2 = fmaf(w, v0.z, tv2);
                tv3 = fmaf(w, v0.w, tv3);
                tv4 = fmaf(w, v1.x, tv4);
                tv5 = fmaf(w, v1.y, tv5);
                tv6 = fmaf(w, v1.z, tv6);
                tv7 = fmaf(w, v1.w, tv7);
            }
        }
    }

    float m0 = sigmoidf_(tg0) * 20.0f - 10.0f;
    float m1 = sigmoidf_(tg1) * 20.0f - 10.0f;
    float m2 = sigmoidf_(tg2) * 20.0f - 10.0f;
    float var = fmaxf(tg3, 0.0f) + log1pf(expf(-fabsf(tg3)));

    float sharp = expf(tv0);
    float nrm = fmaxf(sqrtf(tv1 * tv1 + tv2 * tv2 + tv3 * tv3), 1e-12f);
    float a0 = tv1 / nrm, a1 = tv2 / nrm, a2 = tv3 / nrm;
    float amp0 = sigmoidf_(tv4);
    float amp1 = sigmoidf_(tv5);
    float amp2 = sigmoidf_(tv6);

    float* og = out + (size_t)p * 4;
    og[0] = m0;
    og[1] = m1;
    og[2] = m2;
    og[3] = var;

    float* ov = out + (size_t)n * 4 + (size_t)p * 7;
    ov[0] = sharp;
    ov[1] = a0;
    ov[2] = a1;
    ov[3] = a2;
    ov[4] = amp0;
    ov[5] = amp1;
    ov[6] = amp2;
}

// ---------- fallback (ws too small): round-2 two-table kernel ----------
__global__ __launch_bounds__(256)
void vapl_grid_kernel(const float* __restrict__ pos,
                      const float4* __restrict__ gauss,
                      const float4* __restrict__ vmf,
                      float* __restrict__ out,
                      int n)
{
    int p = blockIdx.x * blockDim.x + threadIdx.x;
    if (p >= n) return;

    float px = pos[3 * p + 0];
    float py = pos[3 * p + 1];
    float pz = pos[3 * p + 2];

    float x = ((px + 10.0f) / 20.0f) * 128.0f;
    float y = ((py + 10.0f) / 20.0f) * 128.0f;
    float z = ((pz + 10.0f) / 20.0f) * 128.0f;

    float fx = floorf(x), fy = floorf(y), fz = floorf(z);
    int ix = (int)fx, iy = (int)fy, iz = (int)fz;
    float wx = x - fx, wy = y - fy, wz = z - fz;

    float ax[4] = {1.0f - wx, 1.0f, 1.0f, wx};
    float ay[4] = {1.0f - wy, 1.0f, 1.0f, wy};
    float az[4] = {1.0f - wz, 1.0f, 1.0f, wz};

    uint32_t hx[4], hy[4], hz[4];
#pragma unroll
    for (int i = 0; i < 4; ++i) {
        hx[i] = (uint32_t)(ix - 1 + i);
        hy[i] = (uint32_t)(iy - 1 + i) * P2;
        hz[i] = (uint32_t)(iz - 1 + i) * P3;
    }

    float tg0 = 0.f, tg1 = 0.f, tg2 = 0.f, tg3 = 0.f;
    float tv0 = 0.f, tv1 = 0.f, tv2 = 0.f, tv3 = 0.f;
    float tv4 = 0.f, tv5 = 0.f, tv6 = 0.f, tv7 = 0.f;

    for (int k = 0; k < 4; ++k) {
        for (int j = 0; j < 4; ++j) {
            uint32_t hyz = hy[j] ^ hz[k];
            float wyz = ay[j] * az[k];
#pragma unroll
            for (int i = 0; i < 4; ++i) {
                uint32_t h = (hx[i] ^ hyz) & TABLE_MASK;
                float w = ax[i] * wyz;
                float4 g  = gauss[h];
                float4 v0 = vmf[(size_t)2 * h];
                float4 v1 = vmf[(size_t)2 * h + 1];
                tg0 = fmaf(w, g.x,  tg0);
                tg1 = fmaf(w, g.y,  tg1);
                tg2 = fmaf(w, g.z,  tg2);
                tg3 = fmaf(w, g.w,  tg3);
                tv0 = fmaf(w, v0.x, tv0);
                tv1 = fmaf(w, v0.y, tv1);
                tv2 = fmaf(w, v0.z, tv2);
                tv3 = fmaf(w, v0.w, tv3);
                tv4 = fmaf(w, v1.x, tv4);
                tv5 = fmaf(w, v1.y, tv5);
                tv6 = fmaf(w, v1.z, tv6);
                tv7 = fmaf(w, v1.w, tv7);
            }
        }
    }

    float m0 = sigmoidf_(tg0) * 20.0f - 10.0f;
    float m1 = sigmoidf_(tg1) * 20.0f - 10.0f;
    float m2 = sigmoidf_(tg2) * 20.0f - 10.0f;
    float var = fmaxf(tg3, 0.0f) + log1pf(expf(-fabsf(tg3)));

    float sharp = expf(tv0);
    float nrm = fmaxf(sqrtf(tv1 * tv1 + tv2 * tv2 + tv3 * tv3), 1e-12f);
    float a0 = tv1 / nrm, a1 = tv2 / nrm, a2 = tv3 / nrm;
    float amp0 = sigmoidf_(tv4);
    float amp1 = sigmoidf_(tv5);
    float amp2 = sigmoidf_(tv6);

    float* og = out + (size_t)p * 4;
    og[0] = m0;
    og[1] = m1;
    og[2] = m2;
    og[3] = var;

    float* ov = out + (size_t)n * 4 + (size_t)p * 7;
    ov[0] = sharp;
    ov[1] = a0;
    ov[2] = a1;
    ov[3] = a2;
    ov[4] = amp0;
    ov[5] = amp1;
    ov[6] = amp2;
}

extern "C" void kernel_launch(void* const* d_in, const int* in_sizes, int n_in,
                              void* d_out, int out_size, void* d_ws, size_t ws_size,
                              hipStream_t stream) {
    const float*  pos   = (const float*)d_in[0];
    const float4* gauss = (const float4*)d_in[1];
    const float4* vmf   = (const float4*)d_in[2];
    float* out = (float*)d_out;
    int n = in_sizes[0] / 3;   // 1048576

    const size_t packed_bytes = (size_t)TABLE_SIZE * 64;   // 256 MB

    dim3 block(256);
    dim3 grid((n + 255) / 256);

    if (ws_size >= packed_bytes) {
        float4* packed = (float4*)d_ws;
        dim3 pgrid((TABLE_SIZE + 255) / 256);
        hipLaunchKernelGGL(pack_tables_kernel, pgrid, block, 0, stream, gauss, vmf, packed);
        hipLaunchKernelGGL(vapl_grid_packed_kernel, grid, block, 0, stream, pos, packed, out, n);
    } else {
        hipLaunchKernelGGL(vapl_grid_kernel, grid, block, 0, stream, pos, gauss, vmf, out, n);
    }
}

// Round 4
// 890.496 us; speedup vs baseline: 3.6337x; 2.6751x over previous
//
#include <hip/hip_runtime.h>
#include <cstdint>

#define TABLE_SIZE (1u << 22)
#define TABLE_MASK 0x3FFFFFu   // 2^22 - 1
#define P2 2654435761u
#define P3 805459861u

#define DIM 134                 // corner coords in [-2,130] -> +2 offset -> [0,132]; 134 for margin
#define NCELLS ((size_t)DIM * DIM * DIM)   // 2,406,104
#define REC 12                  // 12 floats = 48 B per packed record

__device__ __forceinline__ float sigmoidf_(float x) { return 1.0f / (1.0f + expf(-x)); }

// ---------- prepass: materialize dense[cz][cy][cx] = {gauss[h], vmf[h]} (48 B record) ----------
__global__ __launch_bounds__(256)
void build_dense_kernel(const float4* __restrict__ gauss,
                        const float4* __restrict__ vmf,
                        float4* __restrict__ dense)   // NCELLS * 3 float4
{
    uint32_t l = blockIdx.x * blockDim.x + threadIdx.x;
    if (l >= (uint32_t)NCELLS) return;
    uint32_t cx = l % DIM;
    uint32_t t  = l / DIM;
    uint32_t cy = t % DIM;
    uint32_t cz = t / DIM;
    // actual corner coords are (c - 2), hashed after numpy-style uint32 wrap
    uint32_t ux = (uint32_t)((int)cx - 2);
    uint32_t uy = (uint32_t)((int)cy - 2);
    uint32_t uz = (uint32_t)((int)cz - 2);
    uint32_t h = (ux ^ (uy * P2) ^ (uz * P3)) & TABLE_MASK;
    float4 g  = gauss[h];
    float4 v0 = vmf[(size_t)2 * h];
    float4 v1 = vmf[(size_t)2 * h + 1];
    float4* d = dense + (size_t)l * 3;
    d[0] = g;
    d[1] = v0;
    d[2] = v1;
}

// ---------- main: 4x4x4 collapsed stencil over the dense grid (L3-resident) ----------
__global__ __launch_bounds__(256)
void vapl_grid_dense_kernel(const float* __restrict__ pos,
                            const float* __restrict__ dense,
                            float* __restrict__ out,   // [N*4] then [N*7], f32
                            int n)
{
    int p = blockIdx.x * blockDim.x + threadIdx.x;
    if (p >= n) return;

    float px = pos[3 * p + 0];
    float py = pos[3 * p + 1];
    float pz = pos[3 * p + 2];

    float x = ((px + 10.0f) / 20.0f) * 128.0f;
    float y = ((py + 10.0f) / 20.0f) * 128.0f;
    float z = ((pz + 10.0f) / 20.0f) * 128.0f;

    float fx = floorf(x), fy = floorf(y), fz = floorf(z);
    int ix = (int)fx, iy = (int)fy, iz = (int)fz;
    float wx = x - fx, wy = y - fy, wz = z - fz;

    float ax[4] = {1.0f - wx, 1.0f, 1.0f, wx};
    float ay[4] = {1.0f - wy, 1.0f, 1.0f, wy};
    float az[4] = {1.0f - wz, 1.0f, 1.0f, wz};

    // dense coords of the first corner: (i*-1) + 2 = i* + 1
    int bx = ix + 1, by = iy + 1, bz = iz + 1;

    float tg0 = 0.f, tg1 = 0.f, tg2 = 0.f, tg3 = 0.f;
    float tv0 = 0.f, tv1 = 0.f, tv2 = 0.f, tv3 = 0.f;
    float tv4 = 0.f, tv5 = 0.f, tv6 = 0.f, tv7 = 0.f;

    for (int k = 0; k < 4; ++k) {
        for (int j = 0; j < 4; ++j) {
            size_t row = ((size_t)(bz + k) * DIM + (size_t)(by + j)) * DIM + (size_t)bx;
            const float* r = dense + row * REC;
            float wyz = ay[j] * az[k];
#pragma unroll
            for (int i = 0; i < 4; ++i) {
                float w = ax[i] * wyz;
                const float4* rec = (const float4*)(r + (size_t)i * REC);
                float4 g  = rec[0];
                float4 v0 = rec[1];
                float4 v1 = rec[2];
                tg0 = fmaf(w, g.x,  tg0);
                tg1 = fmaf(w, g.y,  tg1);
                tg2 = fmaf(w, g.z,  tg2);
                tg3 = fmaf(w, g.w,  tg3);
                tv0 = fmaf(w, v0.x, tv0);
                tv1 = fmaf(w, v0.y, tv1);
                tv2 = fmaf(w, v0.z, tv2);
                tv3 = fmaf(w, v0.w, tv3);
                tv4 = fmaf(w, v1.x, tv4);
                tv5 = fmaf(w, v1.y, tv5);
                tv6 = fmaf(w, v1.z, tv6);
                tv7 = fmaf(w, v1.w, tv7);
            }
        }
    }

    float m0 = sigmoidf_(tg0) * 20.0f - 10.0f;
    float m1 = sigmoidf_(tg1) * 20.0f - 10.0f;
    float m2 = sigmoidf_(tg2) * 20.0f - 10.0f;
    float var = fmaxf(tg3, 0.0f) + log1pf(expf(-fabsf(tg3)));

    float sharp = expf(tv0);
    float nrm = fmaxf(sqrtf(tv1 * tv1 + tv2 * tv2 + tv3 * tv3), 1e-12f);
    float a0 = tv1 / nrm, a1 = tv2 / nrm, a2 = tv3 / nrm;
    float amp0 = sigmoidf_(tv4);
    float amp1 = sigmoidf_(tv5);
    float amp2 = sigmoidf_(tv6);

    float* og = out + (size_t)p * 4;
    og[0] = m0;
    og[1] = m1;
    og[2] = m2;
    og[3] = var;

    float* ov = out + (size_t)n * 4 + (size_t)p * 7;
    ov[0] = sharp;
    ov[1] = a0;
    ov[2] = a1;
    ov[3] = a2;
    ov[4] = amp0;
    ov[5] = amp1;
    ov[6] = amp2;
}

// ---------- fallback (ws too small): round-2 two-table kernel ----------
__global__ __launch_bounds__(256)
void vapl_grid_kernel(const float* __restrict__ pos,
                      const float4* __restrict__ gauss,
                      const float4* __restrict__ vmf,
                      float* __restrict__ out,
                      int n)
{
    int p = blockIdx.x * blockDim.x + threadIdx.x;
    if (p >= n) return;

    float px = pos[3 * p + 0];
    float py = pos[3 * p + 1];
    float pz = pos[3 * p + 2];

    float x = ((px + 10.0f) / 20.0f) * 128.0f;
    float y = ((py + 10.0f) / 20.0f) * 128.0f;
    float z = ((pz + 10.0f) / 20.0f) * 128.0f;

    float fx = floorf(x), fy = floorf(y), fz = floorf(z);
    int ix = (int)fx, iy = (int)fy, iz = (int)fz;
    float wx = x - fx, wy = y - fy, wz = z - fz;

    float ax[4] = {1.0f - wx, 1.0f, 1.0f, wx};
    float ay[4] = {1.0f - wy, 1.0f, 1.0f, wy};
    float az[4] = {1.0f - wz, 1.0f, 1.0f, wz};

    uint32_t hx[4], hy[4], hz[4];
#pragma unroll
    for (int i = 0; i < 4; ++i) {
        hx[i] = (uint32_t)(ix - 1 + i);
        hy[i] = (uint32_t)(iy - 1 + i) * P2;
        hz[i] = (uint32_t)(iz - 1 + i) * P3;
    }

    float tg0 = 0.f, tg1 = 0.f, tg2 = 0.f, tg3 = 0.f;
    float tv0 = 0.f, tv1 = 0.f, tv2 = 0.f, tv3 = 0.f;
    float tv4 = 0.f, tv5 = 0.f, tv6 = 0.f, tv7 = 0.f;

    for (int k = 0; k < 4; ++k) {
        for (int j = 0; j < 4; ++j) {
            uint32_t hyz = hy[j] ^ hz[k];
            float wyz = ay[j] * az[k];
#pragma unroll
            for (int i = 0; i < 4; ++i) {
                uint32_t h = (hx[i] ^ hyz) & TABLE_MASK;
                float w = ax[i] * wyz;
                float4 g  = gauss[h];
                float4 v0 = vmf[(size_t)2 * h];
                float4 v1 = vmf[(size_t)2 * h + 1];
                tg0 = fmaf(w, g.x,  tg0);
                tg1 = fmaf(w, g.y,  tg1);
                tg2 = fmaf(w, g.z,  tg2);
                tg3 = fmaf(w, g.w,  tg3);
                tv0 = fmaf(w, v0.x, tv0);
                tv1 = fmaf(w, v0.y, tv1);
                tv2 = fmaf(w, v0.z, tv2);
                tv3 = fmaf(w, v0.w, tv3);
                tv4 = fmaf(w, v1.x, tv4);
                tv5 = fmaf(w, v1.y, tv5);
                tv6 = fmaf(w, v1.z, tv6);
                tv7 = fmaf(w, v1.w, tv7);
            }
        }
    }

    float m0 = sigmoidf_(tg0) * 20.0f - 10.0f;
    float m1 = sigmoidf_(tg1) * 20.0f - 10.0f;
    float m2 = sigmoidf_(tg2) * 20.0f - 10.0f;
    float var = fmaxf(tg3, 0.0f) + log1pf(expf(-fabsf(tg3)));

    float sharp = expf(tv0);
    float nrm = fmaxf(sqrtf(tv1 * tv1 + tv2 * tv2 + tv3 * tv3), 1e-12f);
    float a0 = tv1 / nrm, a1 = tv2 / nrm, a2 = tv3 / nrm;
    float amp0 = sigmoidf_(tv4);
    float amp1 = sigmoidf_(tv5);
    float amp2 = sigmoidf_(tv6);

    float* og = out + (size_t)p * 4;
    og[0] = m0;
    og[1] = m1;
    og[2] = m2;
    og[3] = var;

    float* ov = out + (size_t)n * 4 + (size_t)p * 7;
    ov[0] = sharp;
    ov[1] = a0;
    ov[2] = a1;
    ov[3] = a2;
    ov[4] = amp0;
    ov[5] = amp1;
    ov[6] = amp2;
}

extern "C" void kernel_launch(void* const* d_in, const int* in_sizes, int n_in,
                              void* d_out, int out_size, void* d_ws, size_t ws_size,
                              hipStream_t stream) {
    const float*  pos   = (const float*)d_in[0];
    const float4* gauss = (const float4*)d_in[1];
    const float4* vmf   = (const float4*)d_in[2];
    float* out = (float*)d_out;
    int n = in_sizes[0] / 3;   // 1048576

    const size_t dense_bytes = NCELLS * (size_t)REC * sizeof(float);   // ~115.5 MB

    dim3 block(256);
    dim3 grid((n + 255) / 256);

    if (ws_size >= dense_bytes) {
        float4* dense = (float4*)d_ws;
        dim3 bgrid((unsigned)((NCELLS + 255) / 256));
        hipLaunchKernelGGL(build_dense_kernel, bgrid, block, 0, stream, gauss, vmf, dense);
        hipLaunchKernelGGL(vapl_grid_dense_kernel, grid, block, 0, stream,
                           pos, (const float*)dense, out, n);
    } else {
        hipLaunchKernelGGL(vapl_grid_kernel, grid, block, 0, stream, pos, gauss, vmf, out, n);
    }
}

// Round 5
// 434.317 us; speedup vs baseline: 7.4502x; 2.0503x over previous
//
#include <hip/hip_runtime.h>
#include <cstdint>

#define TABLE_MASK 0x3FFFFFu   // 2^22 - 1
#define P2 2654435761u
#define P3 805459861u

#define DIM 134                 // corner coords in [-2,130] -> +2 offset
#define NCELLS ((size_t)DIM * DIM * DIM)   // 2,406,104
#define REC 12                  // 12 floats = 48 B per packed record
#define NBINS (128 * 128)       // sort key: iz*128 + iy

__device__ __forceinline__ float sigmoidf_(float x) { return 1.0f / (1.0f + expf(-x)); }

// ---------- prepass 1: dense[cz][cy][cx] = {gauss[h], vmf[h]} (48 B record) ----------
__global__ __launch_bounds__(256)
void build_dense_kernel(const float4* __restrict__ gauss,
                        const float4* __restrict__ vmf,
                        float4* __restrict__ dense)   // NCELLS * 3 float4
{
    uint32_t l = blockIdx.x * blockDim.x + threadIdx.x;
    if (l >= (uint32_t)NCELLS) return;
    uint32_t cx = l % DIM;
    uint32_t t  = l / DIM;
    uint32_t cy = t % DIM;
    uint32_t cz = t / DIM;
    uint32_t ux = (uint32_t)((int)cx - 2);
    uint32_t uy = (uint32_t)((int)cy - 2);
    uint32_t uz = (uint32_t)((int)cz - 2);
    uint32_t h = (ux ^ (uy * P2) ^ (uz * P3)) & TABLE_MASK;
    float4 g  = gauss[h];
    float4 v0 = vmf[(size_t)2 * h];
    float4 v1 = vmf[(size_t)2 * h + 1];
    float4* d = dense + (size_t)l * 3;
    d[0] = g;
    d[1] = v0;
    d[2] = v1;
}

// ---------- sort machinery ----------
__global__ __launch_bounds__(256)
void zero_hist_kernel(uint32_t* __restrict__ hist)
{
    int i = blockIdx.x * blockDim.x + threadIdx.x;
    if (i < NBINS) hist[i] = 0u;
}

__device__ __forceinline__ int bin_key(const float* __restrict__ pos, int p)
{
    float py = pos[3 * p + 1];
    float pz = pos[3 * p + 2];
    float y = ((py + 10.0f) / 20.0f) * 128.0f;
    float z = ((pz + 10.0f) / 20.0f) * 128.0f;
    int iy = (int)floorf(y);
    int iz = (int)floorf(z);
    iy = min(max(iy, 0), 127);
    iz = min(max(iz, 0), 127);
    return iz * 128 + iy;
}

__global__ __launch_bounds__(256)
void hist_kernel(const float* __restrict__ pos, uint32_t* __restrict__ hist, int n)
{
    int p = blockIdx.x * blockDim.x + threadIdx.x;
    if (p >= n) return;
    atomicAdd(&hist[bin_key(pos, p)], 1u);
}

// single-block exclusive scan over NBINS (16384) elements
__global__ __launch_bounds__(1024)
void scan_kernel(const uint32_t* __restrict__ hist, uint32_t* __restrict__ cursor)
{
    __shared__ uint32_t buf[1024];
    __shared__ uint32_t running;
    int t = threadIdx.x;
    if (t == 0) running = 0u;
    __syncthreads();
    for (int base = 0; base < NBINS; base += 1024) {
        uint32_t v = hist[base + t];
        buf[t] = v;
        __syncthreads();
        for (int off = 1; off < 1024; off <<= 1) {
            uint32_t x = (t >= off) ? buf[t - off] : 0u;
            __syncthreads();
            buf[t] += x;
            __syncthreads();
        }
        uint32_t incl = buf[t];
        uint32_t r0 = running;
        cursor[base + t] = r0 + incl - v;   // exclusive prefix
        __syncthreads();
        if (t == 1023) running = r0 + incl;
        __syncthreads();
    }
}

__global__ __launch_bounds__(256)
void scatter_kernel(const float* __restrict__ pos, uint32_t* __restrict__ cursor,
                    uint32_t* __restrict__ sortedIdx, int n)
{
    int p = blockIdx.x * blockDim.x + threadIdx.x;
    if (p >= n) return;
    uint32_t slot = atomicAdd(&cursor[bin_key(pos, p)], 1u);
    sortedIdx[slot] = (uint32_t)p;
}

// ---------- main: sorted sweep over the dense grid ----------
__global__ __launch_bounds__(256)
void vapl_grid_sorted_kernel(const float* __restrict__ pos,
                             const float* __restrict__ dense,
                             const uint32_t* __restrict__ sortedIdx,
                             float* __restrict__ out,   // [N*4] then [N*7], f32
                             int n)
{
    // XCD-chunked swizzle: XCD k (blocks with bid%8==k) gets contiguous sorted chunk k
    int bid = blockIdx.x;
    int nb  = gridDim.x;
    int b2  = ((nb & 7) == 0) ? ((bid & 7) * (nb >> 3) + (bid >> 3)) : bid;
    int s = b2 * (int)blockDim.x + (int)threadIdx.x;
    if (s >= n) return;
    int p = (int)sortedIdx[s];

    float px = pos[3 * p + 0];
    float py = pos[3 * p + 1];
    float pz = pos[3 * p + 2];

    float x = ((px + 10.0f) / 20.0f) * 128.0f;
    float y = ((py + 10.0f) / 20.0f) * 128.0f;
    float z = ((pz + 10.0f) / 20.0f) * 128.0f;

    float fx = floorf(x), fy = floorf(y), fz = floorf(z);
    int ix = (int)fx, iy = (int)fy, iz = (int)fz;
    float wx = x - fx, wy = y - fy, wz = z - fz;

    float ax[4] = {1.0f - wx, 1.0f, 1.0f, wx};
    float ay[4] = {1.0f - wy, 1.0f, 1.0f, wy};
    float az[4] = {1.0f - wz, 1.0f, 1.0f, wz};

    int bx = ix + 1, by = iy + 1, bz = iz + 1;

    float tg0 = 0.f, tg1 = 0.f, tg2 = 0.f, tg3 = 0.f;
    float tv0 = 0.f, tv1 = 0.f, tv2 = 0.f, tv3 = 0.f;
    float tv4 = 0.f, tv5 = 0.f, tv6 = 0.f, tv7 = 0.f;

    for (int k = 0; k < 4; ++k) {
        for (int j = 0; j < 4; ++j) {
            size_t row = ((size_t)(bz + k) * DIM + (size_t)(by + j)) * DIM + (size_t)bx;
            const float* r = dense + row * REC;
            float wyz = ay[j] * az[k];
#pragma unroll
            for (int i = 0; i < 4; ++i) {
                float w = ax[i] * wyz;
                const float4* rec = (const float4*)(r + (size_t)i * REC);
                float4 g  = rec[0];
                float4 v0 = rec[1];
                float4 v1 = rec[2];
                tg0 = fmaf(w, g.x,  tg0);
                tg1 = fmaf(w, g.y,  tg1);
                tg2 = fmaf(w, g.z,  tg2);
                tg3 = fmaf(w, g.w,  tg3);
                tv0 = fmaf(w, v0.x, tv0);
                tv1 = fmaf(w, v0.y, tv1);
                tv2 = fmaf(w, v0.z, tv2);
                tv3 = fmaf(w, v0.w, tv3);
                tv4 = fmaf(w, v1.x, tv4);
                tv5 = fmaf(w, v1.y, tv5);
                tv6 = fmaf(w, v1.z, tv6);
                tv7 = fmaf(w, v1.w, tv7);
            }
        }
    }

    float m0 = sigmoidf_(tg0) * 20.0f - 10.0f;
    float m1 = sigmoidf_(tg1) * 20.0f - 10.0f;
    float m2 = sigmoidf_(tg2) * 20.0f - 10.0f;
    float var = fmaxf(tg3, 0.0f) + log1pf(expf(-fabsf(tg3)));

    float sharp = expf(tv0);
    float nrm = fmaxf(sqrtf(tv1 * tv1 + tv2 * tv2 + tv3 * tv3), 1e-12f);
    float a0 = tv1 / nrm, a1 = tv2 / nrm, a2 = tv3 / nrm;
    float amp0 = sigmoidf_(tv4);
    float amp1 = sigmoidf_(tv5);
    float amp2 = sigmoidf_(tv6);

    float* og = out + (size_t)p * 4;
    og[0] = m0;
    og[1] = m1;
    og[2] = m2;
    og[3] = var;

    float* ov = out + (size_t)n * 4 + (size_t)p * 7;
    ov[0] = sharp;
    ov[1] = a0;
    ov[2] = a1;
    ov[3] = a2;
    ov[4] = amp0;
    ov[5] = amp1;
    ov[6] = amp2;
}

// ---------- fallback (ws too small): round-2 two-table kernel ----------
__global__ __launch_bounds__(256)
void vapl_grid_kernel(const float* __restrict__ pos,
                      const float4* __restrict__ gauss,
                      const float4* __restrict__ vmf,
                      float* __restrict__ out,
                      int n)
{
    int p = blockIdx.x * blockDim.x + threadIdx.x;
    if (p >= n) return;

    float px = pos[3 * p + 0];
    float py = pos[3 * p + 1];
    float pz = pos[3 * p + 2];

    float x = ((px + 10.0f) / 20.0f) * 128.0f;
    float y = ((py + 10.0f) / 20.0f) * 128.0f;
    float z = ((pz + 10.0f) / 20.0f) * 128.0f;

    float fx = floorf(x), fy = floorf(y), fz = floorf(z);
    int ix = (int)fx, iy = (int)fy, iz = (int)fz;
    float wx = x - fx, wy = y - fy, wz = z - fz;

    float ax[4] = {1.0f - wx, 1.0f, 1.0f, wx};
    float ay[4] = {1.0f - wy, 1.0f, 1.0f, wy};
    float az[4] = {1.0f - wz, 1.0f, 1.0f, wz};

    uint32_t hx[4], hy[4], hz[4];
#pragma unroll
    for (int i = 0; i < 4; ++i) {
        hx[i] = (uint32_t)(ix - 1 + i);
        hy[i] = (uint32_t)(iy - 1 + i) * P2;
        hz[i] = (uint32_t)(iz - 1 + i) * P3;
    }

    float tg0 = 0.f, tg1 = 0.f, tg2 = 0.f, tg3 = 0.f;
    float tv0 = 0.f, tv1 = 0.f, tv2 = 0.f, tv3 = 0.f;
    float tv4 = 0.f, tv5 = 0.f, tv6 = 0.f, tv7 = 0.f;

    for (int k = 0; k < 4; ++k) {
        for (int j = 0; j < 4; ++j) {
            uint32_t hyz = hy[j] ^ hz[k];
            float wyz = ay[j] * az[k];
#pragma unroll
            for (int i = 0; i < 4; ++i) {
                uint32_t h = (hx[i] ^ hyz) & TABLE_MASK;
                float w = ax[i] * wyz;
                float4 g  = gauss[h];
                float4 v0 = vmf[(size_t)2 * h];
                float4 v1 = vmf[(size_t)2 * h + 1];
                tg0 = fmaf(w, g.x,  tg0);
                tg1 = fmaf(w, g.y,  tg1);
                tg2 = fmaf(w, g.z,  tg2);
                tg3 = fmaf(w, g.w,  tg3);
                tv0 = fmaf(w, v0.x, tv0);
                tv1 = fmaf(w, v0.y, tv1);
                tv2 = fmaf(w, v0.z, tv2);
                tv3 = fmaf(w, v0.w, tv3);
                tv4 = fmaf(w, v1.x, tv4);
                tv5 = fmaf(w, v1.y, tv5);
                tv6 = fmaf(w, v1.z, tv6);
                tv7 = fmaf(w, v1.w, tv7);
            }
        }
    }

    float m0 = sigmoidf_(tg0) * 20.0f - 10.0f;
    float m1 = sigmoidf_(tg1) * 20.0f - 10.0f;
    float m2 = sigmoidf_(tg2) * 20.0f - 10.0f;
    float var = fmaxf(tg3, 0.0f) + log1pf(expf(-fabsf(tg3)));

    float sharp = expf(tv0);
    float nrm = fmaxf(sqrtf(tv1 * tv1 + tv2 * tv2 + tv3 * tv3), 1e-12f);
    float a0 = tv1 / nrm, a1 = tv2 / nrm, a2 = tv3 / nrm;
    float amp0 = sigmoidf_(tv4);
    float amp1 = sigmoidf_(tv5);
    float amp2 = sigmoidf_(tv6);

    float* og = out + (size_t)p * 4;
    og[0] = m0;
    og[1] = m1;
    og[2] = m2;
    og[3] = var;

    float* ov = out + (size_t)n * 4 + (size_t)p * 7;
    ov[0] = sharp;
    ov[1] = a0;
    ov[2] = a1;
    ov[3] = a2;
    ov[4] = amp0;
    ov[5] = amp1;
    ov[6] = amp2;
}

extern "C" void kernel_launch(void* const* d_in, const int* in_sizes, int n_in,
                              void* d_out, int out_size, void* d_ws, size_t ws_size,
                              hipStream_t stream) {
    const float*  pos   = (const float*)d_in[0];
    const float4* gauss = (const float4*)d_in[1];
    const float4* vmf   = (const float4*)d_in[2];
    float* out = (float*)d_out;
    int n = in_sizes[0] / 3;   // 1048576

    // d_ws layout
    size_t off = 0;
    const size_t dense_bytes  = NCELLS * (size_t)REC * sizeof(float);   // ~115.5 MB
    char* ws = (char*)d_ws;
    float4* dense = (float4*)(ws + off);           off += dense_bytes;
    off = (off + 255) & ~(size_t)255;
    uint32_t* hist      = (uint32_t*)(ws + off);   off += (size_t)NBINS * 4;
    uint32_t* cursor    = (uint32_t*)(ws + off);   off += (size_t)NBINS * 4;
    uint32_t* sortedIdx = (uint32_t*)(ws + off);   off += (size_t)n * 4;
    const size_t need = off;

    dim3 block(256);
    dim3 grid((n + 255) / 256);

    if (ws_size >= need) {
        dim3 bgrid((unsigned)((NCELLS + 255) / 256));
        hipLaunchKernelGGL(build_dense_kernel, bgrid, block, 0, stream, gauss, vmf, dense);
        hipLaunchKernelGGL(zero_hist_kernel, dim3((NBINS + 255) / 256), block, 0, stream, hist);
        hipLaunchKernelGGL(hist_kernel, grid, block, 0, stream, pos, hist, n);
        hipLaunchKernelGGL(scan_kernel, dim3(1), dim3(1024), 0, stream, hist, cursor);
        hipLaunchKernelGGL(scatter_kernel, grid, block, 0, stream, pos, cursor, sortedIdx, n);
        hipLaunchKernelGGL(vapl_grid_sorted_kernel, grid, block, 0, stream,
                           pos, (const float*)dense, sortedIdx, out, n);
    } else {
        hipLaunchKernelGGL(vapl_grid_kernel, grid, block, 0, stream, pos, gauss, vmf, out, n);
    }
}

// Round 6
// 297.353 us; speedup vs baseline: 10.8819x; 1.4606x over previous
//
#include <hip/hip_runtime.h>
#include <hip/hip_fp16.h>
#include <cstdint>

#define TABLE_MASK 0x3FFFFFu   // 2^22 - 1
#define P2 2654435761u
#define P3 805459861u

#define DIM 134                 // corner coords in [-2,130] -> +2 offset
#define NCELLS ((size_t)DIM * DIM * DIM)   // 2,406,104
#define RECU 8                  // 8 uints = 32 B per packed fp16 record (24 used + 8 pad)
#define NB3 (128 * 128 * 8)     // bins: (iz, iy, ix/16) = 131072
#define SCAN_BLKS (NB3 / 1024)  // 128

__device__ __forceinline__ float sigmoidf_(float x) { return 1.0f / (1.0f + expf(-x)); }

__device__ __forceinline__ float2 h2f2(uint32_t u) {
    __half2 h = *reinterpret_cast<__half2*>(&u);
    return __half22float2(h);
}
__device__ __forceinline__ uint32_t f2h2(float a, float b) {
    __half2 h = __floats2half2_rn(a, b);
    return *reinterpret_cast<uint32_t*>(&h);
}

// ---------- prepass 1: dense fp16 records dense16[cell*8 .. +7] ----------
__global__ __launch_bounds__(256)
void build_dense_kernel(const float4* __restrict__ gauss,
                        const float4* __restrict__ vmf,
                        uint32_t* __restrict__ dense16)
{
    uint32_t l = blockIdx.x * blockDim.x + threadIdx.x;
    if (l >= (uint32_t)NCELLS) return;
    uint32_t cx = l % DIM;
    uint32_t t  = l / DIM;
    uint32_t cy = t % DIM;
    uint32_t cz = t / DIM;
    uint32_t ux = (uint32_t)((int)cx - 2);
    uint32_t uy = (uint32_t)((int)cy - 2);
    uint32_t uz = (uint32_t)((int)cz - 2);
    uint32_t h = (ux ^ (uy * P2) ^ (uz * P3)) & TABLE_MASK;
    float4 g  = gauss[h];
    float4 v0 = vmf[(size_t)2 * h];
    float4 v1 = vmf[(size_t)2 * h + 1];
    uint4 lo, hi;
    lo.x = f2h2(g.x,  g.y);  lo.y = f2h2(g.z,  g.w);
    lo.z = f2h2(v0.x, v0.y); lo.w = f2h2(v0.z, v0.w);
    hi.x = f2h2(v1.x, v1.y); hi.y = f2h2(v1.z, v1.w);
    hi.z = 0u; hi.w = 0u;
    uint32_t* d = dense16 + (size_t)l * RECU;
    *(uint4*)(d)     = lo;
    *(uint4*)(d + 4) = hi;
}

// ---------- sort machinery (3D bins) ----------
__device__ __forceinline__ int bin_key3(float px, float py, float pz)
{
    float x = ((px + 10.0f) / 20.0f) * 128.0f;
    float y = ((py + 10.0f) / 20.0f) * 128.0f;
    float z = ((pz + 10.0f) / 20.0f) * 128.0f;
    int ix = min(max((int)floorf(x), 0), 127);
    int iy = min(max((int)floorf(y), 0), 127);
    int iz = min(max((int)floorf(z), 0), 127);
    return (((iz << 7) + iy) << 3) + (ix >> 4);
}

__global__ __launch_bounds__(256)
void hist_kernel(const float* __restrict__ pos, uint32_t* __restrict__ hist, int n)
{
    int p = blockIdx.x * blockDim.x + threadIdx.x;
    if (p >= n) return;
    int k = bin_key3(pos[3 * p], pos[3 * p + 1], pos[3 * p + 2]);
    atomicAdd(&hist[k], 1u);
}

__global__ __launch_bounds__(1024)
void scanA_kernel(const uint32_t* __restrict__ hist,
                  uint32_t* __restrict__ cursor,
                  uint32_t* __restrict__ sums)
{
    __shared__ uint32_t buf[1024];
    int t = threadIdx.x;
    int base = blockIdx.x * 1024;
    uint32_t v = hist[base + t];
    buf[t] = v;
    __syncthreads();
    for (int off = 1; off < 1024; off <<= 1) {
        uint32_t x = (t >= off) ? buf[t - off] : 0u;
        __syncthreads();
        buf[t] += x;
        __syncthreads();
    }
    cursor[base + t] = buf[t] - v;          // block-local exclusive prefix
    if (t == 1023) sums[blockIdx.x] = buf[t];
}

__global__ __launch_bounds__(SCAN_BLKS)
void scanB_kernel(const uint32_t* __restrict__ sums, uint32_t* __restrict__ offs)
{
    __shared__ uint32_t buf[SCAN_BLKS];
    int t = threadIdx.x;
    uint32_t v = sums[t];
    buf[t] = v;
    __syncthreads();
    for (int off = 1; off < SCAN_BLKS; off <<= 1) {
        uint32_t x = (t >= off) ? buf[t - off] : 0u;
        __syncthreads();
        buf[t] += x;
        __syncthreads();
    }
    offs[t] = buf[t] - v;                   // exclusive prefix of block sums
}

__global__ __launch_bounds__(256)
void scatter_kernel(const float* __restrict__ pos,
                    uint32_t* __restrict__ cursor,
                    const uint32_t* __restrict__ offs,
                    float4* __restrict__ sortedPts, int n)
{
    int p = blockIdx.x * blockDim.x + threadIdx.x;
    if (p >= n) return;
    float px = pos[3 * p], py = pos[3 * p + 1], pz = pos[3 * p + 2];
    int k = bin_key3(px, py, pz);
    uint32_t slot = offs[k >> 10] + atomicAdd(&cursor[k], 1u);
    sortedPts[slot] = make_float4(px, py, pz, __uint_as_float((uint32_t)p));
}

// ---------- main: sorted sweep over the fp16 dense grid ----------
__global__ __launch_bounds__(256, 4)
void vapl_grid_sorted_kernel(const float4* __restrict__ sortedPts,
                             const uint32_t* __restrict__ dense16,
                             float* __restrict__ out,   // [N*4] then [N*7], f32
                             int n)
{
    int bid = blockIdx.x;
    int nb  = gridDim.x;
    int b2  = ((nb & 7) == 0) ? ((bid & 7) * (nb >> 3) + (bid >> 3)) : bid;
    int s = b2 * (int)blockDim.x + (int)threadIdx.x;
    if (s >= n) return;

    float4 pt = sortedPts[s];
    int p = (int)__float_as_uint(pt.w);

    float x = ((pt.x + 10.0f) / 20.0f) * 128.0f;
    float y = ((pt.y + 10.0f) / 20.0f) * 128.0f;
    float z = ((pt.z + 10.0f) / 20.0f) * 128.0f;

    float fx = floorf(x), fy = floorf(y), fz = floorf(z);
    int ix = (int)fx, iy = (int)fy, iz = (int)fz;
    float wx = x - fx, wy = y - fy, wz = z - fz;

    float ax[4] = {1.0f - wx, 1.0f, 1.0f, wx};
    float ay[4] = {1.0f - wy, 1.0f, 1.0f, wy};
    float az[4] = {1.0f - wz, 1.0f, 1.0f, wz};

    int bx = ix + 1, by = iy + 1, bz = iz + 1;

    float tg0 = 0.f, tg1 = 0.f, tg2 = 0.f, tg3 = 0.f;
    float tv0 = 0.f, tv1 = 0.f, tv2 = 0.f, tv3 = 0.f;
    float tv4 = 0.f, tv5 = 0.f, tv6 = 0.f, tv7 = 0.f;

    for (int k = 0; k < 4; ++k) {
        float azk = az[k];
        size_t planeBase = ((size_t)(bz + k) * DIM + (size_t)by) * DIM + (size_t)bx;
#pragma unroll
        for (int j = 0; j < 4; ++j) {
            const uint32_t* r = dense16 + (planeBase + (size_t)j * DIM) * RECU;
            float wyz = ay[j] * azk;
#pragma unroll
            for (int i = 0; i < 4; ++i) {
                uint4 A = *(const uint4*)(r + (size_t)i * RECU);
                uint2 B = *(const uint2*)(r + (size_t)i * RECU + 4);
                float w = ax[i] * wyz;
                float2 f;
                f = h2f2(A.x); tg0 = fmaf(w, f.x, tg0); tg1 = fmaf(w, f.y, tg1);
                f = h2f2(A.y); tg2 = fmaf(w, f.x, tg2); tg3 = fmaf(w, f.y, tg3);
                f = h2f2(A.z); tv0 = fmaf(w, f.x, tv0); tv1 = fmaf(w, f.y, tv1);
                f = h2f2(A.w); tv2 = fmaf(w, f.x, tv2); tv3 = fmaf(w, f.y, tv3);
                f = h2f2(B.x); tv4 = fmaf(w, f.x, tv4); tv5 = fmaf(w, f.y, tv5);
                f = h2f2(B.y); tv6 = fmaf(w, f.x, tv6); tv7 = fmaf(w, f.y, tv7);
            }
        }
    }

    float m0 = sigmoidf_(tg0) * 20.0f - 10.0f;
    float m1 = sigmoidf_(tg1) * 20.0f - 10.0f;
    float m2 = sigmoidf_(tg2) * 20.0f - 10.0f;
    float var = fmaxf(tg3, 0.0f) + log1pf(expf(-fabsf(tg3)));

    float sharp = expf(tv0);
    float nrm = fmaxf(sqrtf(tv1 * tv1 + tv2 * tv2 + tv3 * tv3), 1e-12f);
    float a0 = tv1 / nrm, a1 = tv2 / nrm, a2 = tv3 / nrm;
    float amp0 = sigmoidf_(tv4);
    float amp1 = sigmoidf_(tv5);
    float amp2 = sigmoidf_(tv6);

    float* og = out + (size_t)p * 4;
    *(float4*)og = make_float4(m0, m1, m2, var);

    float* ov = out + (size_t)n * 4 + (size_t)p * 7;
    ov[0] = sharp;
    ov[1] = a0;
    ov[2] = a1;
    ov[3] = a2;
    ov[4] = amp0;
    ov[5] = amp1;
    ov[6] = amp2;
}

// ---------- fallback (ws too small): round-2 two-table kernel ----------
__global__ __launch_bounds__(256)
void vapl_grid_kernel(const float* __restrict__ pos,
                      const float4* __restrict__ gauss,
                      const float4* __restrict__ vmf,
                      float* __restrict__ out,
                      int n)
{
    int p = blockIdx.x * blockDim.x + threadIdx.x;
    if (p >= n) return;

    float px = pos[3 * p + 0];
    float py = pos[3 * p + 1];
    float pz = pos[3 * p + 2];

    float x = ((px + 10.0f) / 20.0f) * 128.0f;
    float y = ((py + 10.0f) / 20.0f) * 128.0f;
    float z = ((pz + 10.0f) / 20.0f) * 128.0f;

    float fx = floorf(x), fy = floorf(y), fz = floorf(z);
    int ix = (int)fx, iy = (int)fy, iz = (int)fz;
    float wx = x - fx, wy = y - fy, wz = z - fz;

    float ax[4] = {1.0f - wx, 1.0f, 1.0f, wx};
    float ay[4] = {1.0f - wy, 1.0f, 1.0f, wy};
    float az[4] = {1.0f - wz, 1.0f, 1.0f, wz};

    uint32_t hx[4], hy[4], hz[4];
#pragma unroll
    for (int i = 0; i < 4; ++i) {
        hx[i] = (uint32_t)(ix - 1 + i);
        hy[i] = (uint32_t)(iy - 1 + i) * P2;
        hz[i] = (uint32_t)(iz - 1 + i) * P3;
    }

    float tg0 = 0.f, tg1 = 0.f, tg2 = 0.f, tg3 = 0.f;
    float tv0 = 0.f, tv1 = 0.f, tv2 = 0.f, tv3 = 0.f;
    float tv4 = 0.f, tv5 = 0.f, tv6 = 0.f, tv7 = 0.f;

    for (int k = 0; k < 4; ++k) {
        for (int j = 0; j < 4; ++j) {
            uint32_t hyz = hy[j] ^ hz[k];
            float wyz = ay[j] * az[k];
#pragma unroll
            for (int i = 0; i < 4; ++i) {
                uint32_t h = (hx[i] ^ hyz) & TABLE_MASK;
                float w = ax[i] * wyz;
                float4 g  = gauss[h];
                float4 v0 = vmf[(size_t)2 * h];
                float4 v1 = vmf[(size_t)2 * h + 1];
                tg0 = fmaf(w, g.x,  tg0);
                tg1 = fmaf(w, g.y,  tg1);
                tg2 = fmaf(w, g.z,  tg2);
                tg3 = fmaf(w, g.w,  tg3);
                tv0 = fmaf(w, v0.x, tv0);
                tv1 = fmaf(w, v0.y, tv1);
                tv2 = fmaf(w, v0.z, tv2);
                tv3 = fmaf(w, v0.w, tv3);
                tv4 = fmaf(w, v1.x, tv4);
                tv5 = fmaf(w, v1.y, tv5);
                tv6 = fmaf(w, v1.z, tv6);
                tv7 = fmaf(w, v1.w, tv7);
            }
        }
    }

    float m0 = sigmoidf_(tg0) * 20.0f - 10.0f;
    float m1 = sigmoidf_(tg1) * 20.0f - 10.0f;
    float m2 = sigmoidf_(tg2) * 20.0f - 10.0f;
    float var = fmaxf(tg3, 0.0f) + log1pf(expf(-fabsf(tg3)));

    float sharp = expf(tv0);
    float nrm = fmaxf(sqrtf(tv1 * tv1 + tv2 * tv2 + tv3 * tv3), 1e-12f);
    float a0 = tv1 / nrm, a1 = tv2 / nrm, a2 = tv3 / nrm;
    float amp0 = sigmoidf_(tv4);
    float amp1 = sigmoidf_(tv5);
    float amp2 = sigmoidf_(tv6);

    float* og = out + (size_t)p * 4;
    og[0] = m0;
    og[1] = m1;
    og[2] = m2;
    og[3] = var;

    float* ov = out + (size_t)n * 4 + (size_t)p * 7;
    ov[0] = sharp;
    ov[1] = a0;
    ov[2] = a1;
    ov[3] = a2;
    ov[4] = amp0;
    ov[5] = amp1;
    ov[6] = amp2;
}

extern "C" void kernel_launch(void* const* d_in, const int* in_sizes, int n_in,
                              void* d_out, int out_size, void* d_ws, size_t ws_size,
                              hipStream_t stream) {
    const float*  pos   = (const float*)d_in[0];
    const float4* gauss = (const float4*)d_in[1];
    const float4* vmf   = (const float4*)d_in[2];
    float* out = (float*)d_out;
    int n = in_sizes[0] / 3;   // 1048576

    // d_ws layout
    size_t off = 0;
    char* ws = (char*)d_ws;
    uint32_t* dense16 = (uint32_t*)(ws + off);  off += NCELLS * RECU * 4;        // ~77 MB
    off = (off + 255) & ~(size_t)255;
    uint32_t* hist    = (uint32_t*)(ws + off);  off += (size_t)NB3 * 4;
    uint32_t* cursor  = (uint32_t*)(ws + off);  off += (size_t)NB3 * 4;
    uint32_t* sums    = (uint32_t*)(ws + off);  off += 256 * 4;
    uint32_t* offs    = (uint32_t*)(ws + off);  off += 256 * 4;
    off = (off + 255) & ~(size_t)255;
    float4* sortedPts = (float4*)(ws + off);    off += (size_t)n * 16;           // 16 MB
    const size_t need = off;

    dim3 block(256);
    dim3 grid((n + 255) / 256);

    if (ws_size >= need) {
        dim3 bgrid((unsigned)((NCELLS + 255) / 256));
        hipLaunchKernelGGL(build_dense_kernel, bgrid, block, 0, stream, gauss, vmf, dense16);
        hipMemsetAsync(hist, 0, (size_t)NB3 * 4, stream);
        hipLaunchKernelGGL(hist_kernel, grid, block, 0, stream, pos, hist, n);
        hipLaunchKernelGGL(scanA_kernel, dim3(SCAN_BLKS), dim3(1024), 0, stream, hist, cursor, sums);
        hipLaunchKernelGGL(scanB_kernel, dim3(1), dim3(SCAN_BLKS), 0, stream, sums, offs);
        hipLaunchKernelGGL(scatter_kernel, grid, block, 0, stream, pos, cursor, offs, sortedPts, n);
        hipLaunchKernelGGL(vapl_grid_sorted_kernel, grid, block, 0, stream,
                           sortedPts, dense16, out, n);
    } else {
        hipLaunchKernelGGL(vapl_grid_kernel, grid, block, 0, stream, pos, gauss, vmf, out, n);
    }
}

// Round 7
// 267.102 us; speedup vs baseline: 12.1143x; 1.1133x over previous
//
#include <hip/hip_runtime.h>
#include <hip/hip_fp16.h>
#include <cstdint>

#define TABLE_MASK 0x3FFFFFu   // 2^22 - 1
#define P2 2654435761u
#define P3 805459861u

#define XD 128                  // exdx x-extent (cx-1, cx in [1,128])
#define YD 132                  // cy in [1,131]
#define ZD 132                  // cz in [1,131]
#define RECU 12                 // 12 uints = 48 B per cell: Ex(6 half2) + Dx(6 half2)
#define NB3 (128 * 128 * 8)     // bins: (iz, iy, ix/16) = 131072
#define SCAN_BLKS (NB3 / 1024)  // 128

__device__ __forceinline__ float sigmoidf_(float x) { return 1.0f / (1.0f + expf(-x)); }

__device__ __forceinline__ uint32_t f2h2(float a, float b) {
    __half2 h = __floats2half2_rn(a, b);
    return *reinterpret_cast<uint32_t*>(&h);
}
__device__ __forceinline__ __half2 u2h2(uint32_t u) {
    return *reinterpret_cast<__half2*>(&u);
}

// ---------- prepass 1: x-combined fp16 volume exdx[cz][cy][cx-1] = {Ex, Dx} ----------
// Ex = r[cx]+r[cx+1]+r[cx+2], Dx = r[cx+3]-r[cx]  (per 12 features)
// Block handles 2 y-rows at fixed cz: 262 hash-gathers -> 256 outputs.
__global__ __launch_bounds__(256)
void build_exdx_kernel(const float4* __restrict__ gauss,
                       const float4* __restrict__ vmf,
                       uint32_t* __restrict__ exdx)
{
    __shared__ float sm[2][131][13];
    int bidx = blockIdx.x;              // 131 z * 66 y-pairs
    int yp = bidx % 66;
    int rz = 1 + bidx / 66;             // [1,131]
    int ry0 = 1 + 2 * yp;               // [1,131] (row1 may overflow -> guarded)
    int t = threadIdx.x;

    for (int l = t; l < 262; l += 256) {
        int row = (l >= 131) ? 1 : 0;
        int cell = l - row * 131;
        int ry = ry0 + row;
        if (ry <= 131) {
            int xc = 1 + cell;
            uint32_t ux = (uint32_t)(xc - 2);
            uint32_t uy = (uint32_t)(ry - 2);
            uint32_t uz = (uint32_t)(rz - 2);
            uint32_t h = (ux ^ (uy * P2) ^ (uz * P3)) & TABLE_MASK;
            float4 g  = gauss[h];
            float4 v0 = vmf[(size_t)2 * h];
            float4 v1 = vmf[(size_t)2 * h + 1];
            float* s = sm[row][cell];
            s[0] = g.x;  s[1] = g.y;  s[2]  = g.z;  s[3]  = g.w;
            s[4] = v0.x; s[5] = v0.y; s[6]  = v0.z; s[7]  = v0.w;
            s[8] = v1.x; s[9] = v1.y; s[10] = v1.z; s[11] = v1.w;
        }
    }
    __syncthreads();

    int row = t >> 7;
    int c   = t & 127;
    int ry  = ry0 + row;
    if (ry > 131) return;

    uint32_t rec[12];
#pragma unroll
    for (int m = 0; m < 6; ++m) {
        float e0 = sm[row][c][2*m]   + sm[row][c+1][2*m]   + sm[row][c+2][2*m];
        float e1 = sm[row][c][2*m+1] + sm[row][c+1][2*m+1] + sm[row][c+2][2*m+1];
        float d0 = sm[row][c+3][2*m]   - sm[row][c][2*m];
        float d1 = sm[row][c+3][2*m+1] - sm[row][c][2*m+1];
        rec[m]     = f2h2(e0, e1);
        rec[6 + m] = f2h2(d0, d1);
    }
    size_t o = (((size_t)rz * YD + (size_t)ry) * XD + (size_t)c) * RECU;
    *(uint4*)(exdx + o)     = make_uint4(rec[0], rec[1], rec[2],  rec[3]);
    *(uint4*)(exdx + o + 4) = make_uint4(rec[4], rec[5], rec[6],  rec[7]);
    *(uint4*)(exdx + o + 8) = make_uint4(rec[8], rec[9], rec[10], rec[11]);
}

// ---------- sort machinery (3D bins) ----------
__device__ __forceinline__ int bin_key3(float px, float py, float pz)
{
    float x = ((px + 10.0f) / 20.0f) * 128.0f;
    float y = ((py + 10.0f) / 20.0f) * 128.0f;
    float z = ((pz + 10.0f) / 20.0f) * 128.0f;
    int ix = min(max((int)floorf(x), 0), 127);
    int iy = min(max((int)floorf(y), 0), 127);
    int iz = min(max((int)floorf(z), 0), 127);
    return (((iz << 7) + iy) << 3) + (ix >> 4);
}

__global__ __launch_bounds__(256)
void hist_kernel(const float* __restrict__ pos, uint32_t* __restrict__ hist, int n)
{
    int p = blockIdx.x * blockDim.x + threadIdx.x;
    if (p >= n) return;
    int k = bin_key3(pos[3 * p], pos[3 * p + 1], pos[3 * p + 2]);
    atomicAdd(&hist[k], 1u);
}

__global__ __launch_bounds__(1024)
void scanA_kernel(const uint32_t* __restrict__ hist,
                  uint32_t* __restrict__ cursor,
                  uint32_t* __restrict__ sums)
{
    __shared__ uint32_t buf[1024];
    int t = threadIdx.x;
    int base = blockIdx.x * 1024;
    uint32_t v = hist[base + t];
    buf[t] = v;
    __syncthreads();
    for (int off = 1; off < 1024; off <<= 1) {
        uint32_t x = (t >= off) ? buf[t - off] : 0u;
        __syncthreads();
        buf[t] += x;
        __syncthreads();
    }
    cursor[base + t] = buf[t] - v;
    if (t == 1023) sums[blockIdx.x] = buf[t];
}

__global__ __launch_bounds__(SCAN_BLKS)
void scanB_kernel(const uint32_t* __restrict__ sums, uint32_t* __restrict__ offs)
{
    __shared__ uint32_t buf[SCAN_BLKS];
    int t = threadIdx.x;
    uint32_t v = sums[t];
    buf[t] = v;
    __syncthreads();
    for (int off = 1; off < SCAN_BLKS; off <<= 1) {
        uint32_t x = (t >= off) ? buf[t - off] : 0u;
        __syncthreads();
        buf[t] += x;
        __syncthreads();
    }
    offs[t] = buf[t] - v;
}

__global__ __launch_bounds__(256)
void scatter_kernel(const float* __restrict__ pos,
                    uint32_t* __restrict__ cursor,
                    const uint32_t* __restrict__ offs,
                    float4* __restrict__ sortedPts, int n)
{
    int p = blockIdx.x * blockDim.x + threadIdx.x;
    if (p >= n) return;
    float px = pos[3 * p], py = pos[3 * p + 1], pz = pos[3 * p + 2];
    int k = bin_key3(px, py, pz);
    uint32_t slot = offs[k >> 10] + atomicAdd(&cursor[k], 1u);
    sortedPts[slot] = make_float4(px, py, pz, __uint_as_float((uint32_t)p));
}

// ---------- main: 16 cell-gathers per point, double-buffered ----------
__device__ __forceinline__ void consume_cell(const uint4& A, const uint4& B, const uint4& C,
                                             __half2 wxh, float w, float* acc)
{
    uint32_t e[6] = {A.x, A.y, A.z, A.w, B.x, B.y};
    uint32_t d[6] = {B.z, B.w, C.x, C.y, C.z, C.w};
#pragma unroll
    for (int m = 0; m < 6; ++m) {
        __half2 v = __hfma2(wxh, u2h2(d[m]), u2h2(e[m]));
        float2 f = __half22float2(v);
        acc[2*m]     = fmaf(w, f.x, acc[2*m]);
        acc[2*m + 1] = fmaf(w, f.y, acc[2*m + 1]);
    }
}

__global__ __launch_bounds__(256, 3)
void vapl_grid_sorted_kernel(const float4* __restrict__ sortedPts,
                             const uint32_t* __restrict__ exdx,
                             float* __restrict__ out,   // [N*4] then [N*7], f32
                             int n)
{
    int bid = blockIdx.x;
    int nb  = gridDim.x;
    int b2  = ((nb & 7) == 0) ? ((bid & 7) * (nb >> 3) + (bid >> 3)) : bid;
    int s = b2 * (int)blockDim.x + (int)threadIdx.x;
    if (s >= n) return;

    float4 pt = sortedPts[s];
    int p = (int)__float_as_uint(pt.w);

    float x = ((pt.x + 10.0f) / 20.0f) * 128.0f;
    float y = ((pt.y + 10.0f) / 20.0f) * 128.0f;
    float z = ((pt.z + 10.0f) / 20.0f) * 128.0f;

    float fx = floorf(x), fy = floorf(y), fz = floorf(z);
    int ix = (int)fx, iy = (int)fy, iz = (int)fz;
    float wx = x - fx, wy = y - fy, wz = z - fz;

    float ay[4] = {1.0f - wy, 1.0f, 1.0f, wy};
    float az[4] = {1.0f - wz, 1.0f, 1.0f, wz};
    __half2 wxh = __float2half2_rn(wx);

    int bx = ix + 1, by = iy + 1, bz = iz + 1;

    uint32_t idx16[16];
    float    w16[16];
#pragma unroll
    for (int k = 0; k < 4; ++k) {
#pragma unroll
        for (int j = 0; j < 4; ++j) {
            idx16[k*4 + j] = (((uint32_t)(bz + k) * YD + (uint32_t)(by + j)) * XD
                              + (uint32_t)(bx - 1)) * RECU;
            w16[k*4 + j] = ay[j] * az[k];
        }
    }

    float acc[12] = {0.f,0.f,0.f,0.f,0.f,0.f,0.f,0.f,0.f,0.f,0.f,0.f};

    uint4 buf[2][4][3];
    // prologue: load batch 0
#pragma unroll
    for (int c = 0; c < 4; ++c) {
        const uint32_t* r = exdx + idx16[c];
        buf[0][c][0] = *(const uint4*)(r);
        buf[0][c][1] = *(const uint4*)(r + 4);
        buf[0][c][2] = *(const uint4*)(r + 8);
    }
#pragma unroll
    for (int b = 0; b < 4; ++b) {
        const int cur = b & 1, nxt = cur ^ 1;
        if (b < 3) {
#pragma unroll
            for (int c = 0; c < 4; ++c) {
                const uint32_t* r = exdx + idx16[(b + 1) * 4 + c];
                buf[nxt][c][0] = *(const uint4*)(r);
                buf[nxt][c][1] = *(const uint4*)(r + 4);
                buf[nxt][c][2] = *(const uint4*)(r + 8);
            }
        }
#pragma unroll
        for (int c = 0; c < 4; ++c) {
            consume_cell(buf[cur][c][0], buf[cur][c][1], buf[cur][c][2],
                         wxh, w16[b*4 + c], acc);
        }
    }

    float m0 = sigmoidf_(acc[0]) * 20.0f - 10.0f;
    float m1 = sigmoidf_(acc[1]) * 20.0f - 10.0f;
    float m2 = sigmoidf_(acc[2]) * 20.0f - 10.0f;
    float var = fmaxf(acc[3], 0.0f) + log1pf(expf(-fabsf(acc[3])));

    float sharp = expf(acc[4]);
    float nrm = fmaxf(sqrtf(acc[5]*acc[5] + acc[6]*acc[6] + acc[7]*acc[7]), 1e-12f);
    float a0 = acc[5] / nrm, a1 = acc[6] / nrm, a2 = acc[7] / nrm;
    float amp0 = sigmoidf_(acc[8]);
    float amp1 = sigmoidf_(acc[9]);
    float amp2 = sigmoidf_(acc[10]);

    float* og = out + (size_t)p * 4;
    *(float4*)og = make_float4(m0, m1, m2, var);

    float* ov = out + (size_t)n * 4 + (size_t)p * 7;
    ov[0] = sharp;
    ov[1] = a0;
    ov[2] = a1;
    ov[3] = a2;
    ov[4] = amp0;
    ov[5] = amp1;
    ov[6] = amp2;
}

// ---------- fallback (ws too small): round-2 two-table kernel ----------
__global__ __launch_bounds__(256)
void vapl_grid_kernel(const float* __restrict__ pos,
                      const float4* __restrict__ gauss,
                      const float4* __restrict__ vmf,
                      float* __restrict__ out,
                      int n)
{
    int p = blockIdx.x * blockDim.x + threadIdx.x;
    if (p >= n) return;

    float px = pos[3 * p + 0];
    float py = pos[3 * p + 1];
    float pz = pos[3 * p + 2];

    float x = ((px + 10.0f) / 20.0f) * 128.0f;
    float y = ((py + 10.0f) / 20.0f) * 128.0f;
    float z = ((pz + 10.0f) / 20.0f) * 128.0f;

    float fx = floorf(x), fy = floorf(y), fz = floorf(z);
    int ix = (int)fx, iy = (int)fy, iz = (int)fz;
    float wx = x - fx, wy = y - fy, wz = z - fz;

    float ax[4] = {1.0f - wx, 1.0f, 1.0f, wx};
    float ay[4] = {1.0f - wy, 1.0f, 1.0f, wy};
    float az[4] = {1.0f - wz, 1.0f, 1.0f, wz};

    uint32_t hx[4], hy[4], hz[4];
#pragma unroll
    for (int i = 0; i < 4; ++i) {
        hx[i] = (uint32_t)(ix - 1 + i);
        hy[i] = (uint32_t)(iy - 1 + i) * P2;
        hz[i] = (uint32_t)(iz - 1 + i) * P3;
    }

    float tg0 = 0.f, tg1 = 0.f, tg2 = 0.f, tg3 = 0.f;
    float tv0 = 0.f, tv1 = 0.f, tv2 = 0.f, tv3 = 0.f;
    float tv4 = 0.f, tv5 = 0.f, tv6 = 0.f, tv7 = 0.f;

    for (int k = 0; k < 4; ++k) {
        for (int j = 0; j < 4; ++j) {
            uint32_t hyz = hy[j] ^ hz[k];
            float wyz = ay[j] * az[k];
#pragma unroll
            for (int i = 0; i < 4; ++i) {
                uint32_t h = (hx[i] ^ hyz) & TABLE_MASK;
                float w = ax[i] * wyz;
                float4 g  = gauss[h];
                float4 v0 = vmf[(size_t)2 * h];
                float4 v1 = vmf[(size_t)2 * h + 1];
                tg0 = fmaf(w, g.x,  tg0);
                tg1 = fmaf(w, g.y,  tg1);
                tg2 = fmaf(w, g.z,  tg2);
                tg3 = fmaf(w, g.w,  tg3);
                tv0 = fmaf(w, v0.x, tv0);
                tv1 = fmaf(w, v0.y, tv1);
                tv2 = fmaf(w, v0.z, tv2);
                tv3 = fmaf(w, v0.w, tv3);
                tv4 = fmaf(w, v1.x, tv4);
                tv5 = fmaf(w, v1.y, tv5);
                tv6 = fmaf(w, v1.z, tv6);
                tv7 = fmaf(w, v1.w, tv7);
            }
        }
    }

    float m0 = sigmoidf_(tg0) * 20.0f - 10.0f;
    float m1 = sigmoidf_(tg1) * 20.0f - 10.0f;
    float m2 = sigmoidf_(tg2) * 20.0f - 10.0f;
    float var = fmaxf(tg3, 0.0f) + log1pf(expf(-fabsf(tg3)));

    float sharp = expf(tv0);
    float nrm = fmaxf(sqrtf(tv1 * tv1 + tv2 * tv2 + tv3 * tv3), 1e-12f);
    float a0 = tv1 / nrm, a1 = tv2 / nrm, a2 = tv3 / nrm;
    float amp0 = sigmoidf_(tv4);
    float amp1 = sigmoidf_(tv5);
    float amp2 = sigmoidf_(tv6);

    float* og = out + (size_t)p * 4;
    og[0] = m0;
    og[1] = m1;
    og[2] = m2;
    og[3] = var;

    float* ov = out + (size_t)n * 4 + (size_t)p * 7;
    ov[0] = sharp;
    ov[1] = a0;
    ov[2] = a1;
    ov[3] = a2;
    ov[4] = amp0;
    ov[5] = amp1;
    ov[6] = amp2;
}

extern "C" void kernel_launch(void* const* d_in, const int* in_sizes, int n_in,
                              void* d_out, int out_size, void* d_ws, size_t ws_size,
                              hipStream_t stream) {
    const float*  pos   = (const float*)d_in[0];
    const float4* gauss = (const float4*)d_in[1];
    const float4* vmf   = (const float4*)d_in[2];
    float* out = (float*)d_out;
    int n = in_sizes[0] / 3;   // 1048576

    // d_ws layout
    size_t off = 0;
    char* ws = (char*)d_ws;
    uint32_t* exdx   = (uint32_t*)(ws + off);  off += (size_t)XD * YD * ZD * RECU * 4;  // ~107 MB
    off = (off + 255) & ~(size_t)255;
    uint32_t* hist   = (uint32_t*)(ws + off);  off += (size_t)NB3 * 4;
    uint32_t* cursor = (uint32_t*)(ws + off);  off += (size_t)NB3 * 4;
    uint32_t* sums   = (uint32_t*)(ws + off);  off += 256 * 4;
    uint32_t* offs   = (uint32_t*)(ws + off);  off += 256 * 4;
    off = (off + 255) & ~(size_t)255;
    float4* sortedPts = (float4*)(ws + off);   off += (size_t)n * 16;                   // 16 MB
    const size_t need = off;

    dim3 block(256);
    dim3 grid((n + 255) / 256);

    if (ws_size >= need) {
        dim3 bgrid(131 * 66);
        hipLaunchKernelGGL(build_exdx_kernel, bgrid, block, 0, stream, gauss, vmf, exdx);
        hipMemsetAsync(hist, 0, (size_t)NB3 * 4, stream);
        hipLaunchKernelGGL(hist_kernel, grid, block, 0, stream, pos, hist, n);
        hipLaunchKernelGGL(scanA_kernel, dim3(SCAN_BLKS), dim3(1024), 0, stream, hist, cursor, sums);
        hipLaunchKernelGGL(scanB_kernel, dim3(1), dim3(SCAN_BLKS), 0, stream, sums, offs);
        hipLaunchKernelGGL(scatter_kernel, grid, block, 0, stream, pos, cursor, offs, sortedPts, n);
        hipLaunchKernelGGL(vapl_grid_sorted_kernel, grid, block, 0, stream,
                           sortedPts, exdx, out, n);
    } else {
        hipLaunchKernelGGL(vapl_grid_kernel, grid, block, 0, stream, pos, gauss, vmf, out, n);
    }
}